// Round 1
// baseline (375.251 us; speedup 1.0000x reference)
//
#include <hip/hip_runtime.h>

// Problem constants (match reference)
#define BB 64
#define MM 2048
#define DD 512
#define CHUNK 64                 // rows of M handled per block
#define SPLITS (MM / CHUNK)      // 32 partials per batch row

// Kernel 1: per (batch b, chunk c) block, find max squared-distance row.
// 256 threads = 4 waves; each wave handles rows r = wave, wave+4, ...
__global__ __launch_bounds__(256) void dist_argmax_kernel(
    const float* __restrict__ inputs,   // [B, D]
    const float* __restrict__ buffer,   // [B, M, D]
    float* __restrict__ ws_d,           // [B, SPLITS]
    int*   __restrict__ ws_i)           // [B, SPLITS]
{
    const int b     = blockIdx.x;
    const int chunk = blockIdx.y;
    const int tid   = threadIdx.x;
    const int lane  = tid & 63;
    const int wave  = tid >> 6;

    // Query slice held in registers: lane covers float4 #lane and #(lane+64)
    const float4* q4 = (const float4*)(inputs + (size_t)b * DD);
    const float4 q0 = q4[lane];
    const float4 q1 = q4[lane + 64];

    const float4* buf4 =
        (const float4*)(buffer + (size_t)b * MM * DD + (size_t)chunk * CHUNK * DD);

    float best_d = -1.0f;
    int   best_i = 0;

    for (int r = wave; r < CHUNK; r += 4) {
        const float4* row = buf4 + (size_t)r * (DD / 4);
        float4 v0 = row[lane];
        float4 v1 = row[lane + 64];
        float s = 0.0f, dx;
        dx = v0.x - q0.x; s += dx * dx;
        dx = v0.y - q0.y; s += dx * dx;
        dx = v0.z - q0.z; s += dx * dx;
        dx = v0.w - q0.w; s += dx * dx;
        dx = v1.x - q1.x; s += dx * dx;
        dx = v1.y - q1.y; s += dx * dx;
        dx = v1.z - q1.z; s += dx * dx;
        dx = v1.w - q1.w; s += dx * dx;
        // wave-wide sum (64 lanes)
        #pragma unroll
        for (int off = 32; off > 0; off >>= 1)
            s += __shfl_down(s, off, 64);
        if (lane == 0) {
            // strictly-greater keeps first occurrence within this wave
            if (s > best_d) { best_d = s; best_i = r; }
        }
    }

    __shared__ float sd[4];
    __shared__ int   si[4];
    if (lane == 0) { sd[wave] = best_d; si[wave] = best_i; }
    __syncthreads();
    if (tid == 0) {
        float bd = sd[0]; int bi = si[0];
        #pragma unroll
        for (int w = 1; w < 4; w++) {
            // tie -> lower row index (first occurrence, jnp.argmax semantics)
            if (sd[w] > bd || (sd[w] == bd && si[w] < bi)) { bd = sd[w]; bi = si[w]; }
        }
        ws_d[b * SPLITS + chunk] = bd;
        ws_i[b * SPLITS + chunk] = chunk * CHUNK + bi;
    }
}

// Kernel 2: reduce the 32 partials per batch row, gather the winning row.
__global__ __launch_bounds__(128) void gather_kernel(
    const float* __restrict__ ws_d,
    const int*   __restrict__ ws_i,
    const float* __restrict__ buffer,
    float*       __restrict__ out)
{
    const int b   = blockIdx.x;
    const int tid = threadIdx.x;
    __shared__ int s_idx;

    if (tid < 64) {
        float d = (tid < SPLITS) ? ws_d[b * SPLITS + tid] : -1.0f;
        int   i = (tid < SPLITS) ? ws_i[b * SPLITS + tid] : 0x7fffffff;
        #pragma unroll
        for (int off = 32; off > 0; off >>= 1) {
            float od = __shfl_down(d, off, 64);
            int   oi = __shfl_down(i, off, 64);
            if (od > d || (od == d && oi < i)) { d = od; i = oi; }
        }
        if (tid == 0) s_idx = i;
    }
    __syncthreads();

    const int idx = s_idx;
    const float4* src = (const float4*)(buffer + ((size_t)b * MM + idx) * DD);
    float4*       dst = (float4*)(out + (size_t)b * DD);
    dst[tid] = src[tid];   // D/4 = 128 float4s, 128 threads
}

extern "C" void kernel_launch(void* const* d_in, const int* in_sizes, int n_in,
                              void* d_out, int out_size, void* d_ws, size_t ws_size,
                              hipStream_t stream) {
    const float* inputs = (const float*)d_in[0];   // [B, D]
    const float* buffer = (const float*)d_in[1];   // [B, M, D]
    float* out  = (float*)d_out;                   // [B, D]
    float* ws_d = (float*)d_ws;                    // [B, SPLITS]
    int*   ws_i = (int*)(ws_d + BB * SPLITS);      // [B, SPLITS]

    dim3 grid(BB, SPLITS);
    dist_argmax_kernel<<<grid, 256, 0, stream>>>(inputs, buffer, ws_d, ws_i);
    gather_kernel<<<BB, 128, 0, stream>>>(ws_d, ws_i, buffer, out);
}